// Round 7
// baseline (453.465 us; speedup 1.0000x reference)
//
#include <hip/hip_runtime.h>

#define N_NODES 50000
#define N_EDGES 800000
#define NODE_F 256
#define EDGE_F 8
#define OUT_F 64
#define M_PAD 50048         // N_NODES rounded to 64
#define GEMM_BLOCKS 782     // M_PAD / 64
#define EDGE_BLOCKS 3125    // N_EDGES / 256

typedef unsigned int u32;
typedef unsigned short u16;
typedef __attribute__((ext_vector_type(8))) short bf16x8;
typedef __attribute__((ext_vector_type(4))) float f32x4;
typedef __attribute__((ext_vector_type(2))) _Float16 h2;

// 32B CSR record: opposite endpoint + f16 edge features, one cacheline slot.
struct __align__(32) Ent { int opp; int p0; int p1; int p2; uint4 fh; };

// ---- bf16 helpers ---------------------------------------------------------
__device__ __forceinline__ u16 bf16r(float x) {
    u32 b = __float_as_uint(x);
    b += 0x7fffu + ((b >> 16) & 1u);
    return (u16)(b >> 16);
}
__device__ __forceinline__ float bl(u32 u) { return __uint_as_float(u << 16); }
__device__ __forceinline__ float bh(u32 u) { return __uint_as_float(u & 0xffff0000u); }

// truncation-pack two f32 -> {bf16 lo, bf16 hi} in one v_perm_b32
__device__ __forceinline__ u32 pktr(float lo, float hi) {
    return __builtin_amdgcn_perm(__float_as_uint(hi), __float_as_uint(lo),
                                 0x07060302);
}
__device__ __forceinline__ bf16x8 pack_bf8(float4 a, float4 b) {
    union { bf16x8 v; u32 u[4]; } r;
    r.u[0] = pktr(a.x, a.y);
    r.u[1] = pktr(a.z, a.w);
    r.u[2] = pktr(b.x, b.y);
    r.u[3] = pktr(b.z, b.w);
    return r.v;
}

// ---- f16 helpers ----------------------------------------------------------
__device__ __forceinline__ u32 pkh2(float a, float b) {
    union { h2 h; u32 u; } cv;
    cv.h[0] = (_Float16)a; cv.h[1] = (_Float16)b;
    return cv.u;
}
__device__ __forceinline__ h2 uh2(u32 u) {
    union { u32 u; h2 h; } cv; cv.u = u; return cv.h;
}
__device__ __forceinline__ float ae_dot(uint4 f, h2 w0, h2 w1, h2 w2, h2 w3) {
#if __has_builtin(__builtin_amdgcn_fdot2)
    float r = __builtin_amdgcn_fdot2(uh2(f.x), w0, 0.f, false);
    r = __builtin_amdgcn_fdot2(uh2(f.y), w1, r, false);
    r = __builtin_amdgcn_fdot2(uh2(f.z), w2, r, false);
    r = __builtin_amdgcn_fdot2(uh2(f.w), w3, r, false);
    return r;
#else
    h2 a0 = uh2(f.x), a1 = uh2(f.y), a2 = uh2(f.z), a3 = uh2(f.w);
    return (float)a0[0]*(float)w0[0] + (float)a0[1]*(float)w0[1]
         + (float)a1[0]*(float)w1[0] + (float)a1[1]*(float)w1[1]
         + (float)a2[0]*(float)w2[0] + (float)a2[1]*(float)w2[1]
         + (float)a3[0]*(float)w3[0] + (float)a3[1]*(float)w3[1];
#endif
}
#define LOAD_WH(c)                                                         \
    h2 wh0, wh1, wh2, wh3;                                                 \
    {                                                                      \
        float4 wa = *(const float4*)&W_ae[(c) * EDGE_F];                   \
        float4 wb = *(const float4*)&W_ae[(c) * EDGE_F + 4];               \
        wh0[0] = (_Float16)wa.x; wh0[1] = (_Float16)wa.y;                  \
        wh1[0] = (_Float16)wa.z; wh1[1] = (_Float16)wa.w;                  \
        wh2[0] = (_Float16)wb.x; wh2[1] = (_Float16)wb.y;                  \
        wh3[0] = (_Float16)wb.z; wh3[1] = (_Float16)wb.w;                  \
    }

// ---------------------------------------------------------------------------
// K1: {4 weights -> Wb bf16 | degree histograms}
// ---------------------------------------------------------------------------
__global__ __launch_bounds__(256) void setup_kernel(
    const int* __restrict__ src_idx, const int* __restrict__ dst_idx,
    const float* __restrict__ W_src, const float* __restrict__ W_attn_src,
    const float* __restrict__ W_attn_dst, const float* __restrict__ W_dst,
    int* __restrict__ hist_src, int* __restrict__ hist_dst,
    u16* __restrict__ Wb)
{
    int b = blockIdx.x;
    if (b < 256) {
        int t = b * 256 + threadIdx.x;                    // < 65536
        int n = t >> 8, k = t & 255;
        int mat = n >> 6, oo = n & 63;
        const float* __restrict__ Ws[4] = {W_src, W_attn_src, W_attn_dst, W_dst};
        Wb[t] = bf16r(Ws[mat][oo * NODE_F + k]);
    } else {
        int e = (b - 256) * 256 + threadIdx.x;
        if (e >= N_EDGES) return;
        atomicAdd(&hist_src[src_idx[e]], 1);
        atomicAdd(&hist_dst[dst_idx[e]], 1);
    }
}

// ---------------------------------------------------------------------------
// K2: two-array exclusive scan
// ---------------------------------------------------------------------------
__global__ __launch_bounds__(512) void scan_kernel(
    const int* __restrict__ hist_dst, const int* __restrict__ hist_src,
    int* __restrict__ off_dst, int* __restrict__ off_src,
    int* __restrict__ cur_dst, int* __restrict__ cur_src)
{
    const int* __restrict__ h = blockIdx.x ? hist_src : hist_dst;
    int* __restrict__ off = blockIdx.x ? off_src : off_dst;
    int* __restrict__ cur = blockIdx.x ? cur_src : cur_dst;

    __shared__ int part[512];
    const int t = threadIdx.x;
    const int CH = (N_NODES + 511) / 512;
    int lo = t * CH, hi = min(lo + CH, N_NODES);
    int sum = 0;
    for (int i = lo; i < hi; ++i) sum += h[i];
    part[t] = sum;
    __syncthreads();
    for (int ofs = 1; ofs < 512; ofs <<= 1) {
        int v = (t >= ofs) ? part[t - ofs] : 0;
        __syncthreads();
        part[t] += v;
        __syncthreads();
    }
    int run = (t == 0) ? 0 : part[t - 1];
    for (int i = lo; i < hi; ++i) {
        off[i] = run;
        cur[i] = run;
        run += h[i];
    }
    if (t == 511) off[N_NODES] = run;
}

// ---------------------------------------------------------------------------
// K3: fused {zero-LDS MFMA GEMM (reads f32 feat, in-reg bf16 truncate) |
//            CSR scatter into 32B Ent records}.
// GEMM: block = 64 rows, 4 waves; wave w -> output matrix w.
//   w=0: fc (f32)  w=1: pack low16 (bf16)  w=2: adst (bf16)  w=3: res+b (f32)
// ---------------------------------------------------------------------------
__global__ __launch_bounds__(256) void gemm_scatter(
    const float* __restrict__ feat, const u16* __restrict__ Wb,
    const float* __restrict__ b_dst,
    float* __restrict__ fc, u32* __restrict__ pack,
    u16* __restrict__ adst_bf, float* __restrict__ res,
    const int* __restrict__ src_idx, const int* __restrict__ dst_idx,
    const float* __restrict__ feat_edge,
    int* __restrict__ cur_src, int* __restrict__ cur_dst,
    Ent* __restrict__ ent_src, Ent* __restrict__ ent_dst)
{
    if (blockIdx.x < GEMM_BLOCKS) {
        const int lane = threadIdx.x & 63;
        const int w = threadIdx.x >> 6;
        const int m0 = blockIdx.x * 64;
        const int lrow = lane & 15;
        const int lk = (lane >> 4) * 8;

        // clamped A row pointers (tail rows read row N-1; outputs discarded)
        const float* Arow[4];
#pragma unroll
        for (int r = 0; r < 4; ++r) {
            int rr = min(m0 + r * 16 + lrow, N_NODES - 1);
            Arow[r] = feat + (size_t)rr * NODE_F + lk;
        }
        const u16* Bbase = Wb + (size_t)(w * 64 + lrow) * NODE_F + lk;

        f32x4 acc[4][4] = {};

#pragma unroll 2
        for (int ks = 0; ks < 8; ++ks) {
            const int k0 = ks * 32;
            bf16x8 a[4], bb[4];
#pragma unroll
            for (int r = 0; r < 4; ++r) {
                float4 a0 = *(const float4*)(Arow[r] + k0);
                float4 a1 = *(const float4*)(Arow[r] + k0 + 4);
                a[r] = pack_bf8(a0, a1);
            }
#pragma unroll
            for (int n = 0; n < 4; ++n)
                bb[n] = *(const bf16x8*)(Bbase + (size_t)n * 16 * NODE_F + k0);
#pragma unroll
            for (int r = 0; r < 4; ++r)
#pragma unroll
                for (int n = 0; n < 4; ++n)
                    acc[r][n] = __builtin_amdgcn_mfma_f32_16x16x32_bf16(
                        a[r], bb[n], acc[r][n], 0, 0, 0);
        }

        const int crow0 = (lane >> 4) * 4;
        const int ccol = lane & 15;
#pragma unroll
        for (int r = 0; r < 4; ++r) {
#pragma unroll
            for (int n = 0; n < 4; ++n) {
                const int col = n * 16 + ccol;
                const float bias = b_dst[col];
#pragma unroll
                for (int j = 0; j < 4; ++j) {
                    int row = m0 + r * 16 + crow0 + j;
                    if (row >= N_NODES) continue;
                    float v = acc[r][n][j];
                    size_t o = (size_t)row * 64 + col;
                    if (w == 0)      fc[o] = v;
                    else if (w == 1) pack[o] = (u32)bf16r(v);
                    else if (w == 2) adst_bf[o] = bf16r(v);
                    else             res[o] = v + bias;
                }
            }
        }
    } else {
        int e = (blockIdx.x - GEMM_BLOCKS) * 256 + threadIdx.x;
        if (e >= N_EDGES) return;
        int s = src_idx[e], d = dst_idx[e];
        float4 a0 = *(const float4*)&feat_edge[(size_t)e * EDGE_F];
        float4 a1 = *(const float4*)&feat_edge[(size_t)e * EDGE_F + 4];
        uint4 fv;
        fv.x = pkh2(a0.x, a0.y);
        fv.y = pkh2(a0.z, a0.w);
        fv.z = pkh2(a1.x, a1.y);
        fv.w = pkh2(a1.z, a1.w);
        int ps = atomicAdd(&cur_src[s], 1);
        ent_src[ps].opp = d;
        ent_src[ps].fh = fv;
        int pd = atomicAdd(&cur_dst[d], 1);
        ent_dst[pd].opp = s;
        ent_dst[pd].fh = fv;
    }
}

// ---------------------------------------------------------------------------
// src pass: ss = sum_out exp(leaky(asrc[n]+adst[d]+ae));
// writes g = fc * rsqrt(ss) into high16 of pack.
// ---------------------------------------------------------------------------
__global__ __launch_bounds__(256) void src_pass(
    const int* __restrict__ off_src, const Ent* __restrict__ ent,
    const float* __restrict__ W_ae,
    u32* __restrict__ pack, const u16* __restrict__ adst_bf,
    const float* __restrict__ fc)
{
    int n = blockIdx.x * 4 + (threadIdx.x >> 6);
    int c = threadIdx.x & 63;

    LOAD_WH(c);
    u32 uown = pack[(size_t)n * 64 + c];
    float ac = bl(uown);

    int beg = __builtin_amdgcn_readfirstlane(off_src[n]);
    int end = __builtin_amdgcn_readfirstlane(off_src[n + 1]);
    float ssum = 0.f;
    int i = beg;
    for (; i + 3 < end; i += 4) {
        int d0 = ent[i].opp, d1 = ent[i+1].opp, d2 = ent[i+2].opp, d3 = ent[i+3].opp;
        uint4 f0 = ent[i].fh, f1 = ent[i+1].fh, f2 = ent[i+2].fh, f3 = ent[i+3].fh;
        float ad0 = __uint_as_float((u32)adst_bf[(size_t)d0 * 64 + c] << 16);
        float ad1 = __uint_as_float((u32)adst_bf[(size_t)d1 * 64 + c] << 16);
        float ad2 = __uint_as_float((u32)adst_bf[(size_t)d2 * 64 + c] << 16);
        float ad3 = __uint_as_float((u32)adst_bf[(size_t)d3 * 64 + c] << 16);
        float e0 = ac + ad0 + ae_dot(f0, wh0, wh1, wh2, wh3);
        float e1 = ac + ad1 + ae_dot(f1, wh0, wh1, wh2, wh3);
        float e2 = ac + ad2 + ae_dot(f2, wh0, wh1, wh2, wh3);
        float e3 = ac + ad3 + ae_dot(f3, wh0, wh1, wh2, wh3);
        e0 = fmaxf(e0, 0.2f * e0);
        e1 = fmaxf(e1, 0.2f * e1);
        e2 = fmaxf(e2, 0.2f * e2);
        e3 = fmaxf(e3, 0.2f * e3);
        ssum += __expf(e0) + __expf(e1) + __expf(e2) + __expf(e3);
    }
    for (; i < end; ++i) {
        int d0 = ent[i].opp;
        uint4 f0 = ent[i].fh;
        float ad0 = __uint_as_float((u32)adst_bf[(size_t)d0 * 64 + c] << 16);
        float e0 = ac + ad0 + ae_dot(f0, wh0, wh1, wh2, wh3);
        e0 = fmaxf(e0, 0.2f * e0);
        ssum += __expf(e0);
    }
    float g = (ssum > 0.f) ? fc[(size_t)n * 64 + c] * rsqrtf(ssum) : 0.f;
    pack[(size_t)n * 64 + c] = (uown & 0xffffu) | ((u32)bf16r(g) << 16);
}

// ---------------------------------------------------------------------------
// fused dst pass: single loop accumulates sd = sum ex, mm = sum ex*g[s];
// msg = mm*rsqrt(sd); layernorm + @W_agg.T + b_agg + res.
// ---------------------------------------------------------------------------
__global__ __launch_bounds__(256) void dst_fused_pass(
    const int* __restrict__ off_dst, const Ent* __restrict__ ent,
    const float* __restrict__ W_ae,
    const u32* __restrict__ pack, const u16* __restrict__ adst_bf,
    const float* __restrict__ scale, const float* __restrict__ offset,
    const float* __restrict__ W_agg, const float* __restrict__ b_agg,
    const float* __restrict__ res, float* __restrict__ out)
{
    __shared__ float hbuf[4][OUT_F];
    int n = blockIdx.x * 4 + (threadIdx.x >> 6);
    int c = threadIdx.x & 63;
    int ln = threadIdx.x >> 6;

    LOAD_WH(c);
    float adc = __uint_as_float((u32)adst_bf[(size_t)n * 64 + c] << 16);

    int beg = __builtin_amdgcn_readfirstlane(off_dst[n]);
    int end = __builtin_amdgcn_readfirstlane(off_dst[n + 1]);
    float sd = 0.f, mm = 0.f;
    int i = beg;
    for (; i + 3 < end; i += 4) {
        int s0 = ent[i].opp, s1 = ent[i+1].opp, s2 = ent[i+2].opp, s3 = ent[i+3].opp;
        uint4 f0 = ent[i].fh, f1 = ent[i+1].fh, f2 = ent[i+2].fh, f3 = ent[i+3].fh;
        u32 u0 = pack[(size_t)s0 * 64 + c];
        u32 u1 = pack[(size_t)s1 * 64 + c];
        u32 u2 = pack[(size_t)s2 * 64 + c];
        u32 u3 = pack[(size_t)s3 * 64 + c];
        float e0 = bl(u0) + adc + ae_dot(f0, wh0, wh1, wh2, wh3);
        float e1 = bl(u1) + adc + ae_dot(f1, wh0, wh1, wh2, wh3);
        float e2 = bl(u2) + adc + ae_dot(f2, wh0, wh1, wh2, wh3);
        float e3 = bl(u3) + adc + ae_dot(f3, wh0, wh1, wh2, wh3);
        e0 = fmaxf(e0, 0.2f * e0);
        e1 = fmaxf(e1, 0.2f * e1);
        e2 = fmaxf(e2, 0.2f * e2);
        e3 = fmaxf(e3, 0.2f * e3);
        float ex0 = __expf(e0), ex1 = __expf(e1), ex2 = __expf(e2), ex3 = __expf(e3);
        sd += ex0 + ex1 + ex2 + ex3;
        mm += ex0 * bh(u0) + ex1 * bh(u1) + ex2 * bh(u2) + ex3 * bh(u3);
    }
    for (; i < end; ++i) {
        int s0 = ent[i].opp;
        uint4 f0 = ent[i].fh;
        u32 u0 = pack[(size_t)s0 * 64 + c];
        float e0 = bl(u0) + adc + ae_dot(f0, wh0, wh1, wh2, wh3);
        e0 = fmaxf(e0, 0.2f * e0);
        float ex0 = __expf(e0);
        sd += ex0;
        mm += ex0 * bh(u0);
    }
    float x = (sd > 0.f) ? mm * rsqrtf(sd) : 0.f;   // msg[n][c]

    float s1 = x, s2 = x * x;
#pragma unroll
    for (int off = 32; off; off >>= 1) {
        s1 += __shfl_xor(s1, off, 64);
        s2 += __shfl_xor(s2, off, 64);
    }
    float mean = s1 * (1.f / OUT_F);
    float var = fmaxf(s2 * (1.f / OUT_F) - mean * mean, 0.f) + 1e-9f;
    float h = (x - mean) * scale[c] * rsqrtf(var) + offset[c];
    hbuf[ln][c] = h;
    // intra-wave LDS RAW; compiler inserts lgkmcnt

    float acc = 0.f;
#pragma unroll
    for (int j = 0; j < OUT_F; j += 4) {
        float4 w = *(const float4*)&W_agg[c * OUT_F + j];
        acc += w.x * hbuf[ln][j] + w.y * hbuf[ln][j + 1]
             + w.z * hbuf[ln][j + 2] + w.w * hbuf[ln][j + 3];
    }
    out[(size_t)n * OUT_F + c] = acc + b_agg[c] + res[(size_t)n * OUT_F + c];
}

// ---------------------------------------------------------------------------
extern "C" void kernel_launch(void* const* d_in, const int* in_sizes, int n_in,
                              void* d_out, int out_size, void* d_ws, size_t ws_size,
                              hipStream_t stream) {
    const float* feat_src    = (const float*)d_in[0];
    const float* feat_edge   = (const float*)d_in[1];
    const int*   src_idx     = (const int*)d_in[2];
    const int*   dst_idx     = (const int*)d_in[3];
    const float* W_src       = (const float*)d_in[4];
    const float* W_dst       = (const float*)d_in[5];
    const float* b_dst       = (const float*)d_in[6];
    const float* W_attn_src  = (const float*)d_in[7];
    const float* W_attn_dst  = (const float*)d_in[8];
    const float* W_attn_edge = (const float*)d_in[9];
    const float* scale       = (const float*)d_in[10];
    const float* offset      = (const float*)d_in[11];
    const float* W_agg       = (const float*)d_in[12];
    const float* b_agg       = (const float*)d_in[13];
    float* out = (float*)d_out;

    const size_t NF = (size_t)N_NODES * OUT_F;   // 3.2e6

    char* base = (char*)d_ws;
    float* fc      = (float*)base;                 base += NF * 4;
    float* res     = (float*)base;                 base += NF * 4;
    u32*   pack    = (u32*)base;                   base += NF * 4;
    u16*   Wb      = (u16*)base;                   base += 256 * 256 * 2;
    u16*   adst_bf = (u16*)base;                   base += NF * 2;
    Ent*   ent_src = (Ent*)base;                   base += (size_t)N_EDGES * 32;
    Ent*   ent_dst = (Ent*)base;                   base += (size_t)N_EDGES * 32;
    int*   hist_dst = (int*)base;                  base += N_NODES * 4;
    int*   hist_src = (int*)base;                  base += N_NODES * 4;
    int*   off_dst  = (int*)base;                  base += (N_NODES + 1) * 4;
    int*   off_src  = (int*)base;                  base += (N_NODES + 1) * 4;
    int*   cur_dst  = (int*)base;                  base += N_NODES * 4;
    int*   cur_src  = (int*)base;                  base += N_NODES * 4;

    hipMemsetAsync(hist_dst, 0, 2 * N_NODES * sizeof(int), stream);

    setup_kernel<<<256 + EDGE_BLOCKS, 256, 0, stream>>>(
        src_idx, dst_idx, W_src, W_attn_src, W_attn_dst, W_dst,
        hist_src, hist_dst, Wb);

    scan_kernel<<<2, 512, 0, stream>>>(hist_dst, hist_src, off_dst, off_src,
                                       cur_dst, cur_src);

    gemm_scatter<<<GEMM_BLOCKS + EDGE_BLOCKS, 256, 0, stream>>>(
        feat_src, Wb, b_dst, fc, pack, adst_bf, res,
        src_idx, dst_idx, feat_edge, cur_src, cur_dst,
        ent_src, ent_dst);

    const int nb = N_NODES / 4;
    src_pass<<<nb, 256, 0, stream>>>(off_src, ent_src, W_attn_edge,
                                     pack, adst_bf, fc);
    dst_fused_pass<<<nb, 256, 0, stream>>>(off_dst, ent_dst, W_attn_edge,
                                           pack, adst_bf, scale, offset,
                                           W_agg, b_agg, res, out);
}

// Round 9
// 452.143 us; speedup vs baseline: 1.0029x; 1.0029x over previous
//
#include <hip/hip_runtime.h>

#define N_NODES 50000
#define N_EDGES 800000
#define NODE_F 256
#define EDGE_F 8
#define OUT_F 64
#define M_PAD 50048         // N_NODES rounded to 64
#define GEMM_BLOCKS 782     // M_PAD / 64
#define EDGE_BLOCKS 3125    // N_EDGES / 256

typedef unsigned int u32;
typedef unsigned short u16;
typedef __attribute__((ext_vector_type(8))) short bf16x8;
typedef __attribute__((ext_vector_type(4))) float f32x4;
typedef __attribute__((ext_vector_type(2))) _Float16 h2;

// 32B CSR record: opposite endpoint + f16 edge features, one cacheline slot.
struct __align__(32) Ent { int opp; int p0; int p1; int p2; uint4 fh; };

// ---- bf16 helpers ---------------------------------------------------------
__device__ __forceinline__ u16 bf16r(float x) {
    u32 b = __float_as_uint(x);
    b += 0x7fffu + ((b >> 16) & 1u);
    return (u16)(b >> 16);
}
__device__ __forceinline__ float bl(u32 u) { return __uint_as_float(u << 16); }
__device__ __forceinline__ float bh(u32 u) { return __uint_as_float(u & 0xffff0000u); }

// truncation-pack two f32 -> {bf16 lo, bf16 hi} in one v_perm_b32
__device__ __forceinline__ u32 pktr(float lo, float hi) {
    return __builtin_amdgcn_perm(__float_as_uint(hi), __float_as_uint(lo),
                                 0x07060302);
}
__device__ __forceinline__ bf16x8 pack_bf8(float4 a, float4 b) {
    union { bf16x8 v; u32 u[4]; } r;
    r.u[0] = pktr(a.x, a.y);
    r.u[1] = pktr(a.z, a.w);
    r.u[2] = pktr(b.x, b.y);
    r.u[3] = pktr(b.z, b.w);
    return r.v;
}

// ---- f16 helpers ----------------------------------------------------------
__device__ __forceinline__ u32 pkh2(float a, float b) {
    union { h2 h; u32 u; } cv;
    cv.h[0] = (_Float16)a; cv.h[1] = (_Float16)b;
    return cv.u;
}
__device__ __forceinline__ h2 uh2(u32 u) {
    union { u32 u; h2 h; } cv; cv.u = u; return cv.h;
}
__device__ __forceinline__ float ae_dot(uint4 f, h2 w0, h2 w1, h2 w2, h2 w3) {
#if __has_builtin(__builtin_amdgcn_fdot2)
    float r = __builtin_amdgcn_fdot2(uh2(f.x), w0, 0.f, false);
    r = __builtin_amdgcn_fdot2(uh2(f.y), w1, r, false);
    r = __builtin_amdgcn_fdot2(uh2(f.z), w2, r, false);
    r = __builtin_amdgcn_fdot2(uh2(f.w), w3, r, false);
    return r;
#else
    h2 a0 = uh2(f.x), a1 = uh2(f.y), a2 = uh2(f.z), a3 = uh2(f.w);
    return (float)a0[0]*(float)w0[0] + (float)a0[1]*(float)w0[1]
         + (float)a1[0]*(float)w1[0] + (float)a1[1]*(float)w1[1]
         + (float)a2[0]*(float)w2[0] + (float)a2[1]*(float)w2[1]
         + (float)a3[0]*(float)w3[0] + (float)a3[1]*(float)w3[1];
#endif
}
#define LOAD_WH(c)                                                         \
    h2 wh0, wh1, wh2, wh3;                                                 \
    {                                                                      \
        float4 wa = *(const float4*)&W_ae[(c) * EDGE_F];                   \
        float4 wb = *(const float4*)&W_ae[(c) * EDGE_F + 4];               \
        wh0[0] = (_Float16)wa.x; wh0[1] = (_Float16)wa.y;                  \
        wh1[0] = (_Float16)wa.z; wh1[1] = (_Float16)wa.w;                  \
        wh2[0] = (_Float16)wb.x; wh2[1] = (_Float16)wb.y;                  \
        wh3[0] = (_Float16)wb.z; wh3[1] = (_Float16)wb.w;                  \
    }

// ---------------------------------------------------------------------------
// K1: {4 weights -> Wb bf16 | degree histograms}
// ---------------------------------------------------------------------------
__global__ __launch_bounds__(256) void setup_kernel(
    const int* __restrict__ src_idx, const int* __restrict__ dst_idx,
    const float* __restrict__ W_src, const float* __restrict__ W_attn_src,
    const float* __restrict__ W_attn_dst, const float* __restrict__ W_dst,
    int* __restrict__ hist_src, int* __restrict__ hist_dst,
    u16* __restrict__ Wb)
{
    int b = blockIdx.x;
    if (b < 256) {
        int t = b * 256 + threadIdx.x;                    // < 65536
        int n = t >> 8, k = t & 255;
        int mat = n >> 6, oo = n & 63;
        const float* __restrict__ Ws[4] = {W_src, W_attn_src, W_attn_dst, W_dst};
        Wb[t] = bf16r(Ws[mat][oo * NODE_F + k]);
    } else {
        int e = (b - 256) * 256 + threadIdx.x;
        if (e >= N_EDGES) return;
        atomicAdd(&hist_src[src_idx[e]], 1);
        atomicAdd(&hist_dst[dst_idx[e]], 1);
    }
}

// ---------------------------------------------------------------------------
// K2: two-array exclusive scan
// ---------------------------------------------------------------------------
__global__ __launch_bounds__(512) void scan_kernel(
    const int* __restrict__ hist_dst, const int* __restrict__ hist_src,
    int* __restrict__ off_dst, int* __restrict__ off_src,
    int* __restrict__ cur_dst, int* __restrict__ cur_src)
{
    const int* __restrict__ h = blockIdx.x ? hist_src : hist_dst;
    int* __restrict__ off = blockIdx.x ? off_src : off_dst;
    int* __restrict__ cur = blockIdx.x ? cur_src : cur_dst;

    __shared__ int part[512];
    const int t = threadIdx.x;
    const int CH = (N_NODES + 511) / 512;
    int lo = t * CH, hi = min(lo + CH, N_NODES);
    int sum = 0;
    for (int i = lo; i < hi; ++i) sum += h[i];
    part[t] = sum;
    __syncthreads();
    for (int ofs = 1; ofs < 512; ofs <<= 1) {
        int v = (t >= ofs) ? part[t - ofs] : 0;
        __syncthreads();
        part[t] += v;
        __syncthreads();
    }
    int run = (t == 0) ? 0 : part[t - 1];
    for (int i = lo; i < hi; ++i) {
        off[i] = run;
        cur[i] = run;
        run += h[i];
    }
    if (t == 511) off[N_NODES] = run;
}

// ---------------------------------------------------------------------------
// K3: fused {zero-LDS MFMA GEMM (reads f32 feat, in-reg bf16 truncate) |
//            CSR scatter into 32B Ent records}.
// GEMM: block = 64 rows, 4 waves; wave w -> output matrix w.
//   w=0: fc (f32)  w=1: pack low16 (bf16)  w=2: adst (bf16)  w=3: res+b (f32)
// ---------------------------------------------------------------------------
__global__ __launch_bounds__(256) void gemm_scatter(
    const float* __restrict__ feat, const u16* __restrict__ Wb,
    const float* __restrict__ b_dst,
    float* __restrict__ fc, u32* __restrict__ pack,
    u16* __restrict__ adst_bf, float* __restrict__ res,
    const int* __restrict__ src_idx, const int* __restrict__ dst_idx,
    const float* __restrict__ feat_edge,
    int* __restrict__ cur_src, int* __restrict__ cur_dst,
    Ent* __restrict__ ent_src, Ent* __restrict__ ent_dst)
{
    if (blockIdx.x < GEMM_BLOCKS) {
        const int lane = threadIdx.x & 63;
        const int w = threadIdx.x >> 6;
        const int m0 = blockIdx.x * 64;
        const int lrow = lane & 15;
        const int lk = (lane >> 4) * 8;

        // clamped A row pointers (tail rows read row N-1; outputs discarded)
        const float* Arow[4];
#pragma unroll
        for (int r = 0; r < 4; ++r) {
            int rr = min(m0 + r * 16 + lrow, N_NODES - 1);
            Arow[r] = feat + (size_t)rr * NODE_F + lk;
        }
        const u16* Bbase = Wb + (size_t)(w * 64 + lrow) * NODE_F + lk;

        f32x4 acc[4][4] = {};

#pragma unroll 2
        for (int ks = 0; ks < 8; ++ks) {
            const int k0 = ks * 32;
            bf16x8 a[4], bb[4];
#pragma unroll
            for (int r = 0; r < 4; ++r) {
                float4 a0 = *(const float4*)(Arow[r] + k0);
                float4 a1 = *(const float4*)(Arow[r] + k0 + 4);
                a[r] = pack_bf8(a0, a1);
            }
#pragma unroll
            for (int n = 0; n < 4; ++n)
                bb[n] = *(const bf16x8*)(Bbase + (size_t)n * 16 * NODE_F + k0);
#pragma unroll
            for (int r = 0; r < 4; ++r)
#pragma unroll
                for (int n = 0; n < 4; ++n)
                    acc[r][n] = __builtin_amdgcn_mfma_f32_16x16x32_bf16(
                        a[r], bb[n], acc[r][n], 0, 0, 0);
        }

        const int crow0 = (lane >> 4) * 4;
        const int ccol = lane & 15;
#pragma unroll
        for (int r = 0; r < 4; ++r) {
#pragma unroll
            for (int n = 0; n < 4; ++n) {
                const int col = n * 16 + ccol;
                const float bias = b_dst[col];
#pragma unroll
                for (int j = 0; j < 4; ++j) {
                    int row = m0 + r * 16 + crow0 + j;
                    if (row >= N_NODES) continue;
                    float v = acc[r][n][j];
                    size_t o = (size_t)row * 64 + col;
                    if (w == 0)      fc[o] = v;
                    else if (w == 1) pack[o] = (u32)bf16r(v);
                    else if (w == 2) adst_bf[o] = bf16r(v);
                    else             res[o] = v + bias;
                }
            }
        }
    } else {
        int e = (blockIdx.x - GEMM_BLOCKS) * 256 + threadIdx.x;
        if (e >= N_EDGES) return;
        int s = src_idx[e], d = dst_idx[e];
        float4 a0 = *(const float4*)&feat_edge[(size_t)e * EDGE_F];
        float4 a1 = *(const float4*)&feat_edge[(size_t)e * EDGE_F + 4];
        uint4 fv;
        fv.x = pkh2(a0.x, a0.y);
        fv.y = pkh2(a0.z, a0.w);
        fv.z = pkh2(a1.x, a1.y);
        fv.w = pkh2(a1.z, a1.w);
        int ps = atomicAdd(&cur_src[s], 1);
        ent_src[ps].opp = d;
        ent_src[ps].fh = fv;
        int pd = atomicAdd(&cur_dst[d], 1);
        ent_dst[pd].opp = s;
        ent_dst[pd].fh = fv;
    }
}

// ---------------------------------------------------------------------------
// K4: src pass (4 nodes / 256-thread block; unroll 8).
// ss = sum_out exp(leaky(asrc[n]+adst[d]+ae)); g = fc*rsqrt(ss) -> pack hi16.
// ---------------------------------------------------------------------------
__global__ __launch_bounds__(256) void src_pass(
    const int* __restrict__ off_src, const Ent* __restrict__ ent,
    const float* __restrict__ W_ae,
    u32* __restrict__ pack, const u16* __restrict__ adst_bf,
    const float* __restrict__ fc)
{
    int n = blockIdx.x * 4 + (threadIdx.x >> 6);
    int c = threadIdx.x & 63;

    LOAD_WH(c);
    u32 uown = pack[(size_t)n * 64 + c];
    float ac = bl(uown);

    int beg = __builtin_amdgcn_readfirstlane(off_src[n]);
    int end = __builtin_amdgcn_readfirstlane(off_src[n + 1]);
    float ssum = 0.f;
    int i = beg;
    for (; i + 7 < end; i += 8) {
        int o[8]; uint4 f[8];
#pragma unroll
        for (int q = 0; q < 8; ++q) { o[q] = ent[i+q].opp; f[q] = ent[i+q].fh; }
        float ad[8];
#pragma unroll
        for (int q = 0; q < 8; ++q)
            ad[q] = __uint_as_float((u32)adst_bf[(size_t)o[q] * 64 + c] << 16);
#pragma unroll
        for (int q = 0; q < 8; ++q) {
            float e = ac + ad[q] + ae_dot(f[q], wh0, wh1, wh2, wh3);
            e = fmaxf(e, 0.2f * e);
            ssum += __expf(e);
        }
    }
    for (; i < end; ++i) {
        int o0 = ent[i].opp;
        uint4 f0 = ent[i].fh;
        float ad0 = __uint_as_float((u32)adst_bf[(size_t)o0 * 64 + c] << 16);
        float e = ac + ad0 + ae_dot(f0, wh0, wh1, wh2, wh3);
        e = fmaxf(e, 0.2f * e);
        ssum += __expf(e);
    }
    float g = (ssum > 0.f) ? fc[(size_t)n * 64 + c] * rsqrtf(ssum) : 0.f;
    pack[(size_t)n * 64 + c] = (uown & 0xffffu) | ((u32)bf16r(g) << 16);
}

// ---------------------------------------------------------------------------
// K5: fused dst pass (4 nodes / 256-thread block; unroll 8).
// sd = sum ex, mm = sum ex*g[s]; msg = mm*rsqrt(sd); LN + W_agg + res.
// ---------------------------------------------------------------------------
__global__ __launch_bounds__(256) void dst_fused_pass(
    const int* __restrict__ off_dst, const Ent* __restrict__ ent,
    const float* __restrict__ W_ae,
    const u32* __restrict__ pack, const u16* __restrict__ adst_bf,
    const float* __restrict__ scale, const float* __restrict__ offset,
    const float* __restrict__ W_agg, const float* __restrict__ b_agg,
    const float* __restrict__ res, float* __restrict__ out)
{
    __shared__ float hbuf[4][OUT_F];
    int n = blockIdx.x * 4 + (threadIdx.x >> 6);
    int c = threadIdx.x & 63;
    int ln = threadIdx.x >> 6;

    LOAD_WH(c);
    float adc = __uint_as_float((u32)adst_bf[(size_t)n * 64 + c] << 16);

    int beg = __builtin_amdgcn_readfirstlane(off_dst[n]);
    int end = __builtin_amdgcn_readfirstlane(off_dst[n + 1]);
    float sd = 0.f, mm = 0.f;
    int i = beg;
    for (; i + 7 < end; i += 8) {
        int o[8]; uint4 f[8];
#pragma unroll
        for (int q = 0; q < 8; ++q) { o[q] = ent[i+q].opp; f[q] = ent[i+q].fh; }
        u32 uu[8];
#pragma unroll
        for (int q = 0; q < 8; ++q) uu[q] = pack[(size_t)o[q] * 64 + c];
#pragma unroll
        for (int q = 0; q < 8; ++q) {
            float e = bl(uu[q]) + adc + ae_dot(f[q], wh0, wh1, wh2, wh3);
            e = fmaxf(e, 0.2f * e);
            float ex = __expf(e);
            sd += ex;
            mm += ex * bh(uu[q]);
        }
    }
    for (; i < end; ++i) {
        int o0 = ent[i].opp;
        uint4 f0 = ent[i].fh;
        u32 u0 = pack[(size_t)o0 * 64 + c];
        float e = bl(u0) + adc + ae_dot(f0, wh0, wh1, wh2, wh3);
        e = fmaxf(e, 0.2f * e);
        float ex = __expf(e);
        sd += ex;
        mm += ex * bh(u0);
    }
    float x = (sd > 0.f) ? mm * rsqrtf(sd) : 0.f;   // msg[n][c]

    float s1 = x, s2 = x * x;
#pragma unroll
    for (int off = 32; off; off >>= 1) {
        s1 += __shfl_xor(s1, off, 64);
        s2 += __shfl_xor(s2, off, 64);
    }
    float mean = s1 * (1.f / OUT_F);
    float var = fmaxf(s2 * (1.f / OUT_F) - mean * mean, 0.f) + 1e-9f;
    float h = (x - mean) * scale[c] * rsqrtf(var) + offset[c];
    hbuf[ln][c] = h;
    // intra-wave LDS RAW; compiler inserts lgkmcnt

    float acc = 0.f;
#pragma unroll
    for (int j = 0; j < OUT_F; j += 4) {
        float4 w = *(const float4*)&W_agg[c * OUT_F + j];
        acc += w.x * hbuf[ln][j] + w.y * hbuf[ln][j + 1]
             + w.z * hbuf[ln][j + 2] + w.w * hbuf[ln][j + 3];
    }
    out[(size_t)n * OUT_F + c] = acc + b_agg[c] + res[(size_t)n * OUT_F + c];
}

// ---------------------------------------------------------------------------
extern "C" void kernel_launch(void* const* d_in, const int* in_sizes, int n_in,
                              void* d_out, int out_size, void* d_ws, size_t ws_size,
                              hipStream_t stream) {
    const float* feat_src    = (const float*)d_in[0];
    const float* feat_edge   = (const float*)d_in[1];
    const int*   src_idx     = (const int*)d_in[2];
    const int*   dst_idx     = (const int*)d_in[3];
    const float* W_src       = (const float*)d_in[4];
    const float* W_dst       = (const float*)d_in[5];
    const float* b_dst       = (const float*)d_in[6];
    const float* W_attn_src  = (const float*)d_in[7];
    const float* W_attn_dst  = (const float*)d_in[8];
    const float* W_attn_edge = (const float*)d_in[9];
    const float* scale       = (const float*)d_in[10];
    const float* offset      = (const float*)d_in[11];
    const float* W_agg       = (const float*)d_in[12];
    const float* b_agg       = (const float*)d_in[13];
    float* out = (float*)d_out;

    const size_t NF = (size_t)N_NODES * OUT_F;   // 3.2e6

    char* base = (char*)d_ws;
    float* fc      = (float*)base;                 base += NF * 4;
    float* res     = (float*)base;                 base += NF * 4;
    u32*   pack    = (u32*)base;                   base += NF * 4;
    u16*   Wb      = (u16*)base;                   base += 256 * 256 * 2;
    u16*   adst_bf = (u16*)base;                   base += NF * 2;
    Ent*   ent_src = (Ent*)base;                   base += (size_t)N_EDGES * 32;
    Ent*   ent_dst = (Ent*)base;                   base += (size_t)N_EDGES * 32;
    int*   hist_dst = (int*)base;                  base += N_NODES * 4;
    int*   hist_src = (int*)base;                  base += N_NODES * 4;
    int*   off_dst  = (int*)base;                  base += (N_NODES + 1) * 4;
    int*   off_src  = (int*)base;                  base += (N_NODES + 1) * 4;
    int*   cur_dst  = (int*)base;                  base += N_NODES * 4;
    int*   cur_src  = (int*)base;                  base += N_NODES * 4;

    hipMemsetAsync(hist_dst, 0, 2 * N_NODES * sizeof(int), stream);

    setup_kernel<<<256 + EDGE_BLOCKS, 256, 0, stream>>>(
        src_idx, dst_idx, W_src, W_attn_src, W_attn_dst, W_dst,
        hist_src, hist_dst, Wb);

    scan_kernel<<<2, 512, 0, stream>>>(hist_dst, hist_src, off_dst, off_src,
                                       cur_dst, cur_src);

    gemm_scatter<<<GEMM_BLOCKS + EDGE_BLOCKS, 256, 0, stream>>>(
        feat_src, Wb, b_dst, fc, pack, adst_bf, res,
        src_idx, dst_idx, feat_edge, cur_src, cur_dst,
        ent_src, ent_dst);

    const int nb = N_NODES / 4;  // 12500
    src_pass<<<nb, 256, 0, stream>>>(off_src, ent_src, W_attn_edge,
                                     pack, adst_bf, fc);
    dst_fused_pass<<<nb, 256, 0, stream>>>(off_dst, ent_dst, W_attn_edge,
                                           pack, adst_bf, scale, offset,
                                           W_agg, b_agg, res, out);
}